// Round 4
// baseline (770.532 us; speedup 1.0000x reference)
//
#include <hip/hip_runtime.h>

#define NN 200000
#define NE 6400000
#define F_IN 20
#define F_OUT 10
#define XPS 16              // xp row stride: 64B, one cache line per gather
#define NEG_SLOPE 0.2f
#define BN_EPS 1e-5f

#define NPB 800             // nodes per coarse bucket
#define NBUCK 250           // 250*800 == NN exactly
#define NBLK 782            // chunk blocks for count/scatter
#define CHUNK 8192          // edges per chunk block (782*8192 >= NE)
#define SZ (NBUCK * NBLK)   // 195500
#define SCANB 1024
#define G1 ((SZ + SCANB - 1) / SCANB)   // 191
#define HSB 240             // stats partial blocks
#define RT 1024             // creduce threads

// ---- workspace float/int offsets ----
#define OFF_C      41
#define OFF_LOOPAE 42
#define OFF_SCALE  64
#define OFF_SHIFT  84
#define OFF_PART   128                      // HSB*40 partials
#define OFF_PEW    (OFF_PART + HSB * 40)
#define OFF_AS     (OFF_PEW + HSB)
#define OFF_AD     (OFF_AS + NN)
#define OFF_XP     (OFF_AD + NN)            // XPS*NN floats, 16B-aligned
#define OFF_SCN    (OFF_XP + XPS * NN)      // SZ+1 ints
#define OFF_BS     (OFF_SCN + SZ + 1)       // 256 ints
#define OFF_M      (((OFF_BS + 256) + 1) & ~1)  // SZ ints; REC overlays (dead after scan)
#define OFF_REC    OFF_M                    // 2*NE ints (8B records)

// exact floor(d/800) for d < 2^30
__device__ __forceinline__ int bucket_of(int d) {
    return (int)(((unsigned long long)(unsigned)d * 343597384ull) >> 38);
}

// ---------------- column stats of h: per-block partials ----------------
__global__ void k_hstats(const float* __restrict__ h, float* __restrict__ part) {
    float s[F_IN], q[F_IN];
#pragma unroll
    for (int f = 0; f < F_IN; ++f) { s[f] = 0.f; q[f] = 0.f; }
    for (int i = blockIdx.x * blockDim.x + threadIdx.x; i < NN;
         i += gridDim.x * blockDim.x) {
        const float4* row = (const float4*)(h + (size_t)i * F_IN);
#pragma unroll
        for (int v = 0; v < 5; ++v) {
            float4 x = row[v];
            int f = v * 4;
            s[f+0] += x.x; q[f+0] += x.x * x.x;
            s[f+1] += x.y; q[f+1] += x.y * x.y;
            s[f+2] += x.z; q[f+2] += x.z * x.z;
            s[f+3] += x.w; q[f+3] += x.w * x.w;
        }
    }
#pragma unroll
    for (int f = 0; f < F_IN; ++f)
        for (int o = 32; o > 0; o >>= 1) {
            s[f] += __shfl_down(s[f], o);
            q[f] += __shfl_down(q[f], o);
        }
    __shared__ float red[4][40];
    int t = threadIdx.x, wave = t >> 6, lane = t & 63;
    if (lane == 0) {
#pragma unroll
        for (int f = 0; f < F_IN; ++f) { red[wave][f] = s[f]; red[wave][F_IN + f] = q[f]; }
    }
    __syncthreads();
    if (t < 40) part[blockIdx.x * 40 + t] = red[0][t] + red[1][t] + red[2][t] + red[3][t];
}

// ---------------- sum of edge_weight: per-block partials ----------------
__global__ void k_ewsum(const float* __restrict__ ew, float* __restrict__ pew) {
    float s = 0.f;
    const float4* e4 = (const float4*)ew;
    const int n4 = NE / 4;
    for (int i = blockIdx.x * blockDim.x + threadIdx.x; i < n4;
         i += gridDim.x * blockDim.x) {
        float4 x = e4[i];
        s += x.x + x.y + x.z + x.w;
    }
    for (int o = 32; o > 0; o >>= 1) s += __shfl_down(s, o);
    __shared__ float red[4];
    int t = threadIdx.x;
    if ((t & 63) == 0) red[t >> 6] = s;
    __syncthreads();
    if (t == 0) pew[blockIdx.x] = red[0] + red[1] + red[2] + red[3];
}

// ---------------- finalize scalar params ----------------
__global__ void k_params(const float* __restrict__ bn_w, const float* __restrict__ bn_b,
                         const float* __restrict__ W_edge, const float* __restrict__ att_edge,
                         const float* __restrict__ part, const float* __restrict__ pew,
                         float* __restrict__ ws) {
    __shared__ float col[40];
    __shared__ float ews;
    int t = threadIdx.x;
    if (t < 40) {
        float s = 0.f;
#pragma unroll 8
        for (int b = 0; b < HSB; ++b) s += part[b * 40 + t];
        col[t] = s;
    }
    if (t == 40) {
        float s = 0.f;
#pragma unroll 8
        for (int b = 0; b < HSB; ++b) s += pew[b];
        ews = s;
    }
    __syncthreads();
    if (t < F_IN) {
        float mu  = col[t] / (float)NN;
        float var = col[F_IN + t] / (float)NN - mu * mu;
        float sc  = bn_w[t] * rsqrtf(var + BN_EPS);
        ws[OFF_SCALE + t] = sc;
        ws[OFF_SHIFT + t] = bn_b[t] - mu * sc;
    }
    if (t == 63) {
        float c = 0.f;
#pragma unroll
        for (int k = 0; k < F_OUT; ++k) c += W_edge[k] * att_edge[k];
        ws[OFF_C] = c;
        ws[OFF_LOOPAE] = c * (ews / (float)NE);
    }
}

// ---------------- per-node: BN + projection + attention terms ----------------
__global__ void k_node(const float* __restrict__ h, const float* __restrict__ W,
                       const float* __restrict__ att_src, const float* __restrict__ att_dst,
                       const float* __restrict__ ws_ro, float* __restrict__ xp,
                       float* __restrict__ a_s, float* __restrict__ a_d) {
    __shared__ float sW[F_OUT * F_IN], sAs[F_OUT], sAd[F_OUT], sSc[F_IN], sSh[F_IN];
    int t = threadIdx.x;
    if (t < F_OUT * F_IN) sW[t] = W[t];
    if (t < F_OUT) { sAs[t] = att_src[t]; sAd[t] = att_dst[t]; }
    if (t >= 224 && t < 224 + F_IN) {
        sSc[t - 224] = ws_ro[OFF_SCALE + (t - 224)];
        sSh[t - 224] = ws_ro[OFF_SHIFT + (t - 224)];
    }
    __syncthreads();
    int i = blockIdx.x * blockDim.x + t;
    if (i >= NN) return;
    float xn[F_IN];
    const float4* row = (const float4*)(h + (size_t)i * F_IN);
#pragma unroll
    for (int v = 0; v < 5; ++v) {
        float4 x = row[v];
        int f = v * 4;
        xn[f+0] = x.x * sSc[f+0] + sSh[f+0];
        xn[f+1] = x.y * sSc[f+1] + sSh[f+1];
        xn[f+2] = x.z * sSc[f+2] + sSh[f+2];
        xn[f+3] = x.w * sSc[f+3] + sSh[f+3];
    }
    float acc[F_OUT];
    float as = 0.f, ad = 0.f;
#pragma unroll
    for (int k = 0; k < F_OUT; ++k) {
        float a = 0.f;
#pragma unroll
        for (int f = 0; f < F_IN; ++f) a += sW[k * F_IN + f] * xn[f];
        acc[k] = a;
        as += a * sAs[k];
        ad += a * sAd[k];
    }
    float4* xr = (float4*)(xp + (size_t)i * XPS);
    xr[0] = make_float4(acc[0], acc[1], acc[2], acc[3]);
    xr[1] = make_float4(acc[4], acc[5], acc[6], acc[7]);
    xr[2] = make_float4(acc[8], acc[9], 0.f, 0.f);
    a_s[i] = as;
    a_d[i] = ad;
}

// ---------------- pass A: per-(bucket, chunk) edge counts ----------------
__global__ void k_bcount(const int* __restrict__ ei, int* __restrict__ M) {
    __shared__ int hist[NBUCK];
    int t = threadIdx.x, blk = blockIdx.x;
    for (int i = t; i < NBUCK; i += 256) hist[i] = 0;
    __syncthreads();
    int base = blk * CHUNK;
    int lim = NE - base; if (lim > CHUNK) lim = CHUNK;
    for (int j = t; j < lim; j += 256) {
        int dst = ei[NE + base + j];
        atomicAdd(&hist[bucket_of(dst)], 1);
    }
    __syncthreads();
    for (int i = t; i < NBUCK; i += 256) M[i * NBLK + blk] = hist[i];
}

// ---------------- scan ----------------
__global__ void k_scan1(const int* __restrict__ M, int* __restrict__ SCN,
                        int* __restrict__ BS) {
    __shared__ int tmp[SCANB];
    int t = threadIdx.x, g = blockIdx.x;
    int idx = g * SCANB + t;
    int v = (idx < SZ) ? M[idx] : 0;
    tmp[t] = v;
    __syncthreads();
    for (int off = 1; off < SCANB; off <<= 1) {
        int x = (t >= off) ? tmp[t - off] : 0;
        __syncthreads();
        tmp[t] += x;
        __syncthreads();
    }
    if (idx < SZ) SCN[idx] = tmp[t] - v;
    if (t == SCANB - 1) BS[g] = tmp[t];
}

__global__ void k_scan2(int* __restrict__ BS, int* __restrict__ SCN) {
    __shared__ int tmp[SCANB];
    int t = threadIdx.x;
    int v = (t < G1) ? BS[t] : 0;
    tmp[t] = v;
    __syncthreads();
    for (int off = 1; off < SCANB; off <<= 1) {
        int x = (t >= off) ? tmp[t - off] : 0;
        __syncthreads();
        tmp[t] += x;
        __syncthreads();
    }
    if (t < G1) BS[t] = tmp[t] - v;
    if (t == 0) SCN[SZ] = NE;
}

__global__ void k_scan3(int* __restrict__ SCN, const int* __restrict__ BS) {
    int idx = blockIdx.x * SCANB + threadIdx.x;
    if (idx < SZ) SCN[idx] += BS[blockIdx.x];
}

// ---------------- pass B: scatter records into coarse-bucket order ----------------
__global__ void k_scatter(const int* __restrict__ ei, const float* __restrict__ ew,
                          const float* __restrict__ ws_ro,
                          const float* __restrict__ a_s, const float* __restrict__ a_d,
                          const int* __restrict__ SCN, uint2* __restrict__ rec) {
    __shared__ int cur[NBUCK];
    int t = threadIdx.x, blk = blockIdx.x;
    for (int i = t; i < NBUCK; i += 256) cur[i] = SCN[i * NBLK + blk];
    __syncthreads();
    float c = ws_ro[OFF_C];
    int base = blk * CHUNK;
    int lim = NE - base; if (lim > CHUNK) lim = CHUNK;
    for (int j = t; j < lim; j += 256) {
        int e = base + j;
        int src = ei[e];
        int dst = ei[NE + e];
        float logit = a_s[src] + a_d[dst] + c * ew[e];
        logit = logit > 0.f ? logit : NEG_SLOPE * logit;
        float ex = __expf(logit);
        int b = bucket_of(dst);
        int local = dst - b * NPB;            // < 800, 10 bits
        int pos = atomicAdd(&cur[b], 1);
        rec[pos] = make_uint2(((unsigned)src << 10) | (unsigned)local,
                              __float_as_uint(ex));
    }
}

// ---------------- pass C: per-coarse-bucket LDS accumulate + epilogue + MLP ----------------
__global__ void __launch_bounds__(RT) k_creduce(
        const float* __restrict__ ws_ro, const int* __restrict__ SCN,
        const uint2* __restrict__ rec, const float* __restrict__ xp,
        const float* __restrict__ a_s, const float* __restrict__ a_d,
        const float* __restrict__ bias,
        const float* __restrict__ fc1w, const float* __restrict__ fc1b,
        const float* __restrict__ fc2w, const float* __restrict__ fc2b,
        const float* __restrict__ fc3w, const float* __restrict__ fc3b,
        float* __restrict__ out) {
    __shared__ float acc[NPB * 11];          // [local*11 + k]; k=0 den, 1..10 num
    __shared__ float s1[100], s2[100], s3[100], sb[F_OUT], sb1[F_OUT], sb2[F_OUT], sb3[F_OUT];
    int t = threadIdx.x, b = blockIdx.x;
    for (int i = t; i < NPB * 11; i += RT) acc[i] = 0.f;
    if (t < 100) { s1[t] = fc1w[t]; s2[t] = fc2w[t]; s3[t] = fc3w[t]; }
    if (t >= 128 && t < 128 + F_OUT) {
        int k = t - 128;
        sb[k] = bias[k]; sb1[k] = fc1b[k]; sb2[k] = fc2b[k]; sb3[k] = fc3b[k];
    }
    __syncthreads();
    int start = SCN[b * NBLK];
    int end   = SCN[(b + 1) * NBLK];
    int i = start + t;
    for (; i + RT < end; i += 2 * RT) {
        uint2 r1 = rec[i];
        uint2 r2 = rec[i + RT];
        float ex1 = __uint_as_float(r1.y);
        float ex2 = __uint_as_float(r2.y);
        const float4* p1 = (const float4*)(xp + (size_t)(r1.x >> 10) * XPS);
        const float4* p2 = (const float4*)(xp + (size_t)(r2.x >> 10) * XPS);
        float4 a0 = p1[0], a1 = p1[1], a2 = p1[2];
        float4 b0 = p2[0], b1 = p2[1], b2 = p2[2];
        float* q1 = acc + (r1.x & 1023u) * 11;
        float* q2 = acc + (r2.x & 1023u) * 11;
        atomicAdd(q1 + 0, ex1);
        atomicAdd(q1 + 1, ex1 * a0.x); atomicAdd(q1 + 2, ex1 * a0.y);
        atomicAdd(q1 + 3, ex1 * a0.z); atomicAdd(q1 + 4, ex1 * a0.w);
        atomicAdd(q1 + 5, ex1 * a1.x); atomicAdd(q1 + 6, ex1 * a1.y);
        atomicAdd(q1 + 7, ex1 * a1.z); atomicAdd(q1 + 8, ex1 * a1.w);
        atomicAdd(q1 + 9, ex1 * a2.x); atomicAdd(q1 + 10, ex1 * a2.y);
        atomicAdd(q2 + 0, ex2);
        atomicAdd(q2 + 1, ex2 * b0.x); atomicAdd(q2 + 2, ex2 * b0.y);
        atomicAdd(q2 + 3, ex2 * b0.z); atomicAdd(q2 + 4, ex2 * b0.w);
        atomicAdd(q2 + 5, ex2 * b1.x); atomicAdd(q2 + 6, ex2 * b1.y);
        atomicAdd(q2 + 7, ex2 * b1.z); atomicAdd(q2 + 8, ex2 * b1.w);
        atomicAdd(q2 + 9, ex2 * b2.x); atomicAdd(q2 + 10, ex2 * b2.y);
    }
    if (i < end) {
        uint2 r1 = rec[i];
        float ex1 = __uint_as_float(r1.y);
        const float4* p1 = (const float4*)(xp + (size_t)(r1.x >> 10) * XPS);
        float4 a0 = p1[0], a1 = p1[1], a2 = p1[2];
        float* q1 = acc + (r1.x & 1023u) * 11;
        atomicAdd(q1 + 0, ex1);
        atomicAdd(q1 + 1, ex1 * a0.x); atomicAdd(q1 + 2, ex1 * a0.y);
        atomicAdd(q1 + 3, ex1 * a0.z); atomicAdd(q1 + 4, ex1 * a0.w);
        atomicAdd(q1 + 5, ex1 * a1.x); atomicAdd(q1 + 6, ex1 * a1.y);
        atomicAdd(q1 + 7, ex1 * a1.z); atomicAdd(q1 + 8, ex1 * a1.w);
        atomicAdd(q1 + 9, ex1 * a2.x); atomicAdd(q1 + 10, ex1 * a2.y);
    }
    __syncthreads();
    if (t >= NPB) return;
    int node = b * NPB + t;                  // < NN always (250*800 == NN)
    float l = a_s[node] + a_d[node] + ws_ro[OFF_LOOPAE];
    l = l > 0.f ? l : NEG_SLOPE * l;
    float exs = __expf(l);
    float inv = 1.0f / (acc[t * 11] + exs);
    const float* xn = xp + (size_t)node * XPS;
    float o[F_OUT], y1[F_OUT], y2[F_OUT];
#pragma unroll
    for (int k = 0; k < F_OUT; ++k) {
        o[k] = (acc[t * 11 + 1 + k] + exs * xn[k]) * inv + sb[k];
        out[(size_t)node * F_OUT + k] = fmaxf(o[k], 0.f);   // embeddings
    }
#pragma unroll
    for (int k = 0; k < F_OUT; ++k) {
        float a = sb1[k];
#pragma unroll
        for (int jj = 0; jj < F_OUT; ++jj) a += s1[k * F_OUT + jj] * o[jj];
        y1[k] = fmaxf(a, 0.f);
    }
#pragma unroll
    for (int k = 0; k < F_OUT; ++k) {
        float a = sb2[k];
#pragma unroll
        for (int jj = 0; jj < F_OUT; ++jj) a += s2[k * F_OUT + jj] * y1[jj];
        y2[k] = fmaxf(a, 0.f);
    }
#pragma unroll
    for (int k = 0; k < F_OUT; ++k) {
        float a = sb3[k];
#pragma unroll
        for (int jj = 0; jj < F_OUT; ++jj) a += s3[k * F_OUT + jj] * y2[jj];
        out[(size_t)NN * F_OUT + (size_t)node * F_OUT + k] = a;   // y
    }
}

extern "C" void kernel_launch(void* const* d_in, const int* in_sizes, int n_in,
                              void* d_out, int out_size, void* d_ws, size_t ws_size,
                              hipStream_t stream) {
    const float* h        = (const float*)d_in[0];
    const int*   ei       = (const int*)  d_in[1];
    const float* ew       = (const float*)d_in[2];
    const float* bn_w     = (const float*)d_in[3];
    const float* bn_b     = (const float*)d_in[4];
    const float* W        = (const float*)d_in[5];
    const float* att_src  = (const float*)d_in[6];
    const float* att_dst  = (const float*)d_in[7];
    const float* att_edge = (const float*)d_in[8];
    const float* W_edge   = (const float*)d_in[9];
    const float* bias     = (const float*)d_in[10];
    const float* fc1w     = (const float*)d_in[11];
    const float* fc1b     = (const float*)d_in[12];
    const float* fc2w     = (const float*)d_in[13];
    const float* fc2b     = (const float*)d_in[14];
    const float* fc3w     = (const float*)d_in[15];
    const float* fc3b     = (const float*)d_in[16];
    float* ws  = (float*)d_ws;
    int*   wsi = (int*)d_ws;
    float* out = (float*)d_out;

    k_hstats<<<HSB, 256, 0, stream>>>(h, ws + OFF_PART);
    k_ewsum <<<HSB, 256, 0, stream>>>(ew, ws + OFF_PEW);
    k_params<<<1, 64, 0, stream>>>(bn_w, bn_b, W_edge, att_edge,
                                   ws + OFF_PART, ws + OFF_PEW, ws);
    k_node  <<<(NN + 255) / 256, 256, 0, stream>>>(h, W, att_src, att_dst, ws,
                                                   ws + OFF_XP, ws + OFF_AS, ws + OFF_AD);
    k_bcount<<<NBLK, 256, 0, stream>>>(ei, wsi + OFF_M);
    k_scan1 <<<G1, SCANB, 0, stream>>>(wsi + OFF_M, wsi + OFF_SCN, wsi + OFF_BS);
    k_scan2 <<<1, SCANB, 0, stream>>>(wsi + OFF_BS, wsi + OFF_SCN);
    k_scan3 <<<G1, SCANB, 0, stream>>>(wsi + OFF_SCN, wsi + OFF_BS);
    k_scatter<<<NBLK, 256, 0, stream>>>(ei, ew, ws, ws + OFF_AS, ws + OFF_AD,
                                        wsi + OFF_SCN, (uint2*)(wsi + OFF_REC));
    k_creduce<<<NBUCK, RT, 0, stream>>>(ws, wsi + OFF_SCN, (const uint2*)(wsi + OFF_REC),
                                        ws + OFF_XP, ws + OFF_AS, ws + OFF_AD,
                                        bias, fc1w, fc1b, fc2w, fc2b, fc3w, fc3b, out);
}